// Round 5
// baseline (657.671 us; speedup 1.0000x reference)
//
#include <hip/hip_runtime.h>
#include <hip/hip_bf16.h>
#include <stdint.h>

#define D_IN 118
#define D_OUT 64
#define KPAD 128
#define BM 128
#define XS_STRIDE 136  // bf16 units; 68 dwords -> quad-phase LDS reads 2-way (free)
#define MAXSEG 16      // per-block LDS segment window (4 KB)

typedef __attribute__((ext_vector_type(8))) short bf16x8;
typedef __attribute__((ext_vector_type(4))) float floatx4;

// round-to-nearest-even fp32 -> bf16 (for W, cost irrelevant)
__device__ __forceinline__ uint16_t f2bf(float f) {
    uint32_t u;
    __builtin_memcpy(&u, &f, 4);
    return (uint16_t)((u + 0x7fffu + ((u >> 16) & 1u)) >> 16);
}

// cheap 2xfp32 -> packed bf16x2: +0x8000 (round-nearest ties-away) + v_perm
__device__ __forceinline__ uint32_t pack2(float a, float b) {
    uint32_t ua, ub;
    __builtin_memcpy(&ua, &a, 4);
    __builtin_memcpy(&ub, &b, 4);
    ua += 0x8000u;
    ub += 0x8000u;
    return __builtin_amdgcn_perm(ub, ua, 0x07060302);  // low=hi16(a), high=hi16(b)
}

// W -> bf16 [64 x 128] + zero the output accumulator
__global__ void wconv(const float* __restrict__ W, ushort* __restrict__ Wt,
                      float* __restrict__ out, int out_elems) {
    int idx = blockIdx.x * 256 + threadIdx.x;  // 8192 threads
    if (idx < D_OUT * KPAD) {
        int o = idx >> 7, k = idx & 127;
        float v = (k < D_IN) ? W[o * D_IN + k] : 0.f;
        Wt[idx] = f2bf(v);
    }
    for (int i = idx; i < out_elems; i += D_OUT * KPAD)
        out[i] = 0.f;
}

__global__ __launch_bounds__(256, 4) void fused_main(
    const float* __restrict__ x, const ushort* __restrict__ Wt,
    const float* __restrict__ bias, const int* __restrict__ batch,
    float* __restrict__ out, int n_atoms, int chunk)
{
    __shared__ __align__(16) ushort xs[BM * XS_STRIDE];  // 34 KB
    __shared__ int ids[BM];
    __shared__ float segacc[MAXSEG * 64];                // 4 KB

    // XCD-locality swizzle: consecutive atom-tiles (which share segments, and
    // therefore out[] cache lines) land on the SAME XCD so their atomics stay
    // in one L2. Round-robin dispatch: XCD = blockIdx % 8 (m09 heuristic).
    const int tile = (blockIdx.x & 7) * chunk + (blockIdx.x >> 3);
    const int atom0 = tile * BM;
    if (atom0 >= n_atoms) return;  // uniform early-exit for grid padding

    const int tid = threadIdx.x;

    if (tid < BM) {
        int a = atom0 + tid;
        ids[tid] = (a < n_atoms) ? batch[a] : -1;
    }
#pragma unroll
    for (int i = 0; i < (MAXSEG * 64) / 256; ++i)
        segacc[i * 256 + tid] = 0.0f;

    // ---- stage x -> bf16 LDS tile [128 rows x 128 K], float4 loads ----
#pragma unroll
    for (int ph = 0; ph < 8; ++ph) {
        int tau = ph * 256 + tid;
        int m = tau >> 4, c = tau & 15;
        long row = atom0 + m;
        bool rok = row < n_atoms;
        const float* src = x + row * (long)D_IN + c * 8;
        float4 v0 = make_float4(0.f, 0.f, 0.f, 0.f);
        float4 v1 = make_float4(0.f, 0.f, 0.f, 0.f);
        if (rok) {
            if (c < 14) {                       // k 0..111: fully in-row
                v0 = *reinterpret_cast<const float4*>(src);
                v1 = *reinterpret_cast<const float4*>(src + 4);
            } else if (c == 14) {               // k 112..119: 118,119 are pad
                v0 = *reinterpret_cast<const float4*>(src);
                if (row + 1 < n_atoms) {        // safe to over-read into next row
                    v1 = *reinterpret_cast<const float4*>(src + 4);
                    v1.z = 0.f;
                    v1.w = 0.f;
                } else {                        // very last row: no over-read
                    float2 t = *reinterpret_cast<const float2*>(src + 4);
                    v1.x = t.x;
                    v1.y = t.y;
                }
            }                                   // c == 15: all pad (zeros)
        }
        uint4 pkd;
        pkd.x = pack2(v0.x, v0.y);
        pkd.y = pack2(v0.z, v0.w);
        pkd.z = pack2(v1.x, v1.y);
        pkd.w = pack2(v1.z, v1.w);
        *reinterpret_cast<uint4*>(&xs[m * XS_STRIDE + c * 8]) = pkd;
    }

    const int lane = tid & 63;
    const int wv = tid >> 6;
    const int n = lane & 15;   // MFMA A-row / B-col / D-col
    const int q = lane >> 4;   // quad

    __syncthreads();

    floatx4 acc[2][4];
#pragma unroll
    for (int mt = 0; mt < 2; ++mt)
#pragma unroll
        for (int ot = 0; ot < 4; ++ot)
            acc[mt][ot] = (floatx4){0.f, 0.f, 0.f, 0.f};

    // ---- MFMA: wave covers atoms [wv*32, wv*32+32) x all 64 outputs ----
    // B loaded on-demand (Wt is 16 KB, L1-hot) to keep VGPRs under 128
#pragma unroll
    for (int ks = 0; ks < 4; ++ks) {
        bf16x8 afrag[2];
#pragma unroll
        for (int mt = 0; mt < 2; ++mt) {
            int row = wv * 32 + mt * 16 + n;  // A[m=lane&15][k=q*8+j]
            afrag[mt] = *reinterpret_cast<const bf16x8*>(
                &xs[row * XS_STRIDE + ks * 32 + q * 8]);
        }
#pragma unroll
        for (int ot = 0; ot < 4; ++ot) {
            bf16x8 bfrag = *reinterpret_cast<const bf16x8*>(
                Wt + (ot * 16 + n) * KPAD + ks * 32 + q * 8);
            acc[0][ot] = __builtin_amdgcn_mfma_f32_16x16x32_bf16(
                afrag[0], bfrag, acc[0][ot], 0, 0, 0);
            acc[1][ot] = __builtin_amdgcn_mfma_f32_16x16x32_bf16(
                afrag[1], bfrag, acc[1][ot], 0, 0, 0);
        }
    }

    // ---- epilogue: bias + relu + sorted-run flush -> LDS segacc ----
    float bv[4];
#pragma unroll
    for (int ot = 0; ot < 4; ++ot) bv[ot] = bias[ot * 16 + n];

    const int s_first = ids[0];
    float racc[4] = {0.f, 0.f, 0.f, 0.f};
    int cur = ids[wv * 32 + q * 4];
#pragma unroll
    for (int mt = 0; mt < 2; ++mt) {
#pragma unroll
        for (int reg = 0; reg < 4; ++reg) {
            int r = wv * 32 + mt * 16 + q * 4 + reg;
            int id = ids[r];  // same addr across quad -> LDS broadcast
            if (id != cur) {
                if (cur >= 0) {
                    int si = cur - s_first;
                    if (si < MAXSEG) {
#pragma unroll
                        for (int ot = 0; ot < 4; ++ot)
                            atomicAdd(&segacc[si * 64 + ot * 16 + n], racc[ot]);
                    } else {
#pragma unroll
                        for (int ot = 0; ot < 4; ++ot)
                            atomicAdd(&out[cur * 64 + ot * 16 + n], racc[ot]);
                    }
                }
                cur = id;
                racc[0] = racc[1] = racc[2] = racc[3] = 0.f;
            }
#pragma unroll
            for (int ot = 0; ot < 4; ++ot)
                racc[ot] += fmaxf(acc[mt][ot][reg] + bv[ot], 0.f);
        }
    }
    if (cur >= 0) {
        int si = cur - s_first;
        if (si < MAXSEG) {
#pragma unroll
            for (int ot = 0; ot < 4; ++ot)
                atomicAdd(&segacc[si * 64 + ot * 16 + n], racc[ot]);
        } else {
#pragma unroll
            for (int ot = 0; ot < 4; ++ot)
                atomicAdd(&out[cur * 64 + ot * 16 + n], racc[ot]);
        }
    }

    // ---- flush block-level segment sums (1 atomic per nonzero seg-col) ----
    __syncthreads();
#pragma unroll
    for (int i0 = 0; i0 < (MAXSEG * 64) / 256; ++i0) {
        int i = i0 * 256 + tid;
        float v = segacc[i];
        if (v != 0.0f)
            atomicAdd(&out[(s_first + (i >> 6)) * 64 + (i & 63)], v);
    }
}

__global__ void finalize(float* __restrict__ out, int nseg) {
    int row = blockIdx.x * 4 + (threadIdx.x >> 6);
    int lane = threadIdx.x & 63;
    if (row >= nseg) return;
    float v = fmaxf(out[row * 64 + lane], 0.f);
    float m = v;
#pragma unroll
    for (int off = 32; off > 0; off >>= 1)
        m = fmaxf(m, __shfl_xor(m, off, 64));
    out[row * 64 + lane] = v / m;
}

extern "C" void kernel_launch(void* const* d_in, const int* in_sizes, int n_in,
                              void* d_out, int out_size, void* d_ws, size_t ws_size,
                              hipStream_t stream) {
    const float* x = (const float*)d_in[0];
    const float* W = (const float*)d_in[1];
    const float* b = (const float*)d_in[2];
    const int* batch = (const int*)d_in[3];
    int n_atoms = in_sizes[0] / D_IN;
    int nseg = out_size / D_OUT;
    float* out = (float*)d_out;
    ushort* Wt = (ushort*)d_ws;  // 16 KB

    wconv<<<dim3(32), dim3(256), 0, stream>>>(W, Wt, out, out_size);
    int ntiles = (n_atoms + BM - 1) / BM;
    int chunk = (ntiles + 7) / 8;          // tiles per XCD stripe
    int nblocks = chunk * 8;               // padded grid; extras early-exit
    fused_main<<<dim3(nblocks), dim3(256), 0, stream>>>(x, Wt, b, batch, out,
                                                        n_atoms, chunk);
    finalize<<<dim3((nseg + 3) / 4), dim3(256), 0, stream>>>(out, nseg);
}